// Round 8
// baseline (147.129 us; speedup 1.0000x reference)
//
#include <hip/hip_runtime.h>

// SingleStageDetector, R8. f32 I/O; both GEMMs via bf16 MFMA.
// Structure: prep_w (tiny: W1/W2 -> fragment-ready bf16 images in ws) +
// fused_main (grid 512 = image x hw-half, 512 thr = 8 waves):
//   stage F 32-hw slice -> 80KB LDS (F read exactly once device-wide)
//   -> barrier-free 40-step MFMA K-loop (A from W1f global, B from LDS,
//      XOR-swizzled conflict-free ds_read_b128)
//   -> h (bias+leaky, bf16-packed) -> aliased LDS
//   -> GEMM2 via MFMA (W2f frags) + branchy epilogue
//   -> IoU: g-per-lane, register-only, coalesced 160B stores.
// N-split (hw) keeps GEMM2's K block-local: zero cross-block deps, 2 launches.

#define CIN_  1280
#define HW_   49
#define HID_  128
#define OUTD_ 65
#define NGT_  40
#define NP_   441

// flat output offsets (elements), reference return order
#define CONF_OFF 0
#define OFFS_OFF 112896   // 256*9*49
#define CLS_OFF  564480   // + 256*9*4*49
#define IOU_OFF  815360   // + 256*20*49 ; total 5,331,200

// ws layout (u32): W1f frags ((K32*8+mt)*64+lane)*4+sub, then W2f frags
#define WS_W1F_U32 81920u
#define WS_W2F_U32 5120u
#define WS_NEED ((WS_W1F_U32 + WS_W2F_U32) * 4u)

typedef __bf16 bf16x8 __attribute__((ext_vector_type(8)));
typedef float  f32x4  __attribute__((ext_vector_type(4)));

__device__ __forceinline__ unsigned pack2bf(float lo, float hi) {
    unsigned a = __float_as_uint(lo);
    unsigned b = __float_as_uint(hi);
    a = (a + 0x7FFFu + ((a >> 16) & 1u)) >> 16;   // RNE f32->bf16
    b = (b + 0x7FFFu + ((b >> 16) & 1u)) >> 16;
    return a | (b << 16);
}
__device__ __forceinline__ float sigmoidf_(float v) { return 1.f / (1.f + __expf(-v)); }

__device__ __forceinline__ bf16x8 ld_frag(const unsigned* p) {
    union { uint4 u; bf16x8 v; } x;
    x.u = *(const uint4*)p;                       // 16B-aligned ds_read_b128
    return x.v;
}
__device__ __forceinline__ bf16x8 as_bf(uint4 u) {
    union { uint4 u; bf16x8 v; } x; x.u = u; return x.v;
}

// ---------------------------------------------------------------------------
// prep_w: W1 (128,1280) + W2 (65,128) -> fragment-ready bf16 images.
// W1f: frag f = K32*8+mt: (lane,sub) = pack(W1[mt*16+(lane&15)]
//      [K32*32+(lane>>4)*8+sub*2 .. +1]).  W2f: f2 = ks2*5+mt2, rows>=65 zero.
// ---------------------------------------------------------------------------
__global__ __launch_bounds__(256) void prep_w(
    const float* __restrict__ W1, const float* __restrict__ W2,
    unsigned* __restrict__ ws)
{
    int X = blockIdx.x * 256 + threadIdx.x;       // 0..87039
    if (X < (int)WS_W1F_U32) {
        int sub = X & 3, lane = (X >> 2) & 63, f = X >> 8;
        int mt = f & 7, K32 = f >> 3;
        int o = mt * 16 + (lane & 15);
        int c = K32 * 32 + (lane >> 4) * 8 + sub * 2;
        float2 v = *(const float2*)(W1 + o * CIN_ + c);
        ws[X] = pack2bf(v.x, v.y);
    } else {
        int Y = X - (int)WS_W1F_U32;              // 0..5119
        int sub = Y & 3, lane = (Y >> 2) & 63, f = Y >> 8;
        int mt2 = f % 5, ks2 = f / 5;
        int o2 = mt2 * 16 + (lane & 15);
        int c = ks2 * 32 + (lane >> 4) * 8 + sub * 2;
        unsigned val = 0;
        if (o2 < OUTD_) {
            float2 v = *(const float2*)(W2 + o2 * HID_ + c);
            val = pack2bf(v.x, v.y);
        }
        ws[WS_W1F_U32 + Y] = val;
    }
}

// ---------------------------------------------------------------------------
// fused_main: block = (b, half). LDS: smF 32 rows x 640 u32 (stride 640, XOR
// swizzle on 16B blocks: phys_cb = cb ^ (row&7) -> frag reads & stage writes
// both conflict-free). smHT (32x68 u32) aliases smF after the K-loop barrier.
// Wave w = GEMM1 m-tile w (o rows 16w..16w+15); nt 0/1 = hw-local 0..15/16..31.
// Pad hw rows (>=49) staged as zeros -> pad columns are clean zeros, discarded.
// ---------------------------------------------------------------------------
__global__ __launch_bounds__(512, 4) void fused_main(
    const float* __restrict__ F,     // (256,1280,7,7)
    const float* __restrict__ grd,   // (256,7,7,2)
    const float* __restrict__ bbox,  // (256,40,5)
    const float* __restrict__ anc,   // (9,2)
    const unsigned* __restrict__ wsW,
    const float* __restrict__ B1,    // (128,)
    const float* __restrict__ B2,    // (65,)
    float* __restrict__ out)
{
    __shared__ __align__(16) unsigned lds[32 * 640];   // 81,920 B
    unsigned* smHT = lds;                              // 32*68 u32, aliased

    const int tid  = threadIdx.x;
    const int b    = blockIdx.x >> 1;
    const int half = blockIdx.x & 1;
    const int lane = tid & 63;
    const int w    = tid >> 6;         // 0..7 = GEMM1 m-tile
    const int quad = lane >> 4;
    const int m16  = lane & 15;
    const int hw0  = half * 32;

    const float* Fb = F + b * (CIN_ * HW_);

    // ---- stage F hw-slice: rows 0..31 (hw = hw0+row), 640 bf16-pair cols ----
    // thread i -> cp = i>>5 (0..639), row = i&31. Wave = 2 c-pairs x 32 hw:
    // loads are 128B row-runs (sector-aligned). Pad rows -> 0.
    #pragma unroll 4
    for (int it = 0; it < 40; ++it) {
        int i   = it * 512 + tid;
        int cp  = i >> 5;
        int row = i & 31;
        int hw  = hw0 + row;
        unsigned v = 0;
        if (hw < HW_) {
            float f0 = Fb[(2 * cp) * HW_ + hw];
            float f1 = Fb[(2 * cp + 1) * HW_ + hw];
            v = pack2bf(f0, f1);
        }
        int cb = cp >> 2, sub = cp & 3;
        lds[row * 640 + ((cb ^ (row & 7)) << 2) + sub] = v;
    }
    __syncthreads();

    // ---- GEMM1 K-loop: 40 steps, barrier-free ----
    const uint4* Ap = (const uint4*)wsW + w * 64 + lane;   // + K32*8*64
    const unsigned* r0b = lds + m16 * 640;                 // nt0 row
    const unsigned* r1b = lds + (16 + m16) * 640;          // nt1 row ((16+m16)&7 == m16&7)
    const int swz = (m16 & 7);

    f32x4 acc0 = (f32x4)(0.f), acc1 = (f32x4)(0.f);
    uint4 a = Ap[0];
    for (int k = 0; k < 40; ++k) {
        uint4 an;
        if (k < 39) an = Ap[(k + 1) * 512];                // prefetch next A
        int off = ((k * 4 + quad) ^ swz) << 2;
        bf16x8 A = as_bf(a);
        bf16x8 b0 = ld_frag(r0b + off);
        bf16x8 b1 = ld_frag(r1b + off);
        acc0 = __builtin_amdgcn_mfma_f32_16x16x32_bf16(A, b0, acc0, 0, 0, 0);
        acc1 = __builtin_amdgcn_mfma_f32_16x16x32_bf16(A, b1, acc1, 0, 0, 0);
        a = an;
    }

    // prefetch GEMM2 A-frags (global, independent of LDS)
    const int m2a = w % 5, nt2a = w / 5;                   // tile w of 10
    const uint4* A2p = (const uint4*)(wsW + WS_W1F_U32) + m2a * 64 + lane;
    uint4 a20 = A2p[0], a21 = A2p[320], a22 = A2p[640], a23 = A2p[960];

    __syncthreads();   // all smF reads done; safe to alias smHT

    // ---- h: bias + leaky, packed o-pairs -> smHT[hwlocal*68 + o/2] ----
    #pragma unroll
    for (int nt = 0; nt < 2; ++nt) {
        f32x4 ac = nt ? acc1 : acc0;
        int r0 = nt * 16 + m16;
        #pragma unroll
        for (int rp = 0; rp < 2; ++rp) {
            int o0 = w * 16 + quad * 4 + 2 * rp;
            float v0 = ac[2 * rp]     + B1[o0];
            float v1 = ac[2 * rp + 1] + B1[o0 + 1];
            v0 = v0 > 0.f ? v0 : 0.01f * v0;
            v1 = v1 > 0.f ? v1 : 0.01f * v1;
            smHT[r0 * 68 + (o0 >> 1)] = pack2bf(v0, v1);
        }
    }
    __syncthreads();   // smHT ready

    // ---- GEMM2: tile (m2, nt2); wave w -> tile w; waves 0,1 also tiles 8,9 ----
    {
        f32x4 c2 = (f32x4)(0.f);
        const unsigned* Bb = smHT + (nt2a * 16 + m16) * 68 + quad * 4;
        c2 = __builtin_amdgcn_mfma_f32_16x16x32_bf16(as_bf(a20), ld_frag(Bb +  0), c2, 0, 0, 0);
        c2 = __builtin_amdgcn_mfma_f32_16x16x32_bf16(as_bf(a21), ld_frag(Bb + 16), c2, 0, 0, 0);
        c2 = __builtin_amdgcn_mfma_f32_16x16x32_bf16(as_bf(a22), ld_frag(Bb + 32), c2, 0, 0, 0);
        c2 = __builtin_amdgcn_mfma_f32_16x16x32_bf16(as_bf(a23), ld_frag(Bb + 48), c2, 0, 0, 0);
        int hw = hw0 + nt2a * 16 + m16;
        if (hw < HW_) {
            #pragma unroll
            for (int r = 0; r < 4; ++r) {
                int o2 = m2a * 16 + quad * 4 + r;
                if (o2 >= OUTD_) continue;
                float aa = c2[r] + B2[o2];
                unsigned dst; float val;
                if (o2 < 36) {
                    int an9 = o2 >> 2, kk = o2 & 3;
                    val = (kk < 2) ? (sigmoidf_(aa) - 0.5f) : aa;
                    dst = OFFS_OFF + b * 1764 + an9 * 196 + kk * 49 + hw;
                } else if (o2 < 45) {
                    val = sigmoidf_(aa);
                    dst = CONF_OFF + b * 441 + (o2 - 36) * 49 + hw;
                } else {
                    val = aa;
                    dst = CLS_OFF + b * 980 + (o2 - 45) * 49 + hw;
                }
                out[dst] = val;
            }
        }
    }
    if (w < 2) {       // tiles 8,9: m2 = 3+w, nt2 = 1
        const int m2b = 3 + w;
        const uint4* A3p = (const uint4*)(wsW + WS_W1F_U32) + m2b * 64 + lane;
        uint4 b20 = A3p[0], b21 = A3p[320], b22 = A3p[640], b23 = A3p[960];
        f32x4 c2 = (f32x4)(0.f);
        const unsigned* Bb = smHT + (16 + m16) * 68 + quad * 4;
        c2 = __builtin_amdgcn_mfma_f32_16x16x32_bf16(as_bf(b20), ld_frag(Bb +  0), c2, 0, 0, 0);
        c2 = __builtin_amdgcn_mfma_f32_16x16x32_bf16(as_bf(b21), ld_frag(Bb + 16), c2, 0, 0, 0);
        c2 = __builtin_amdgcn_mfma_f32_16x16x32_bf16(as_bf(b22), ld_frag(Bb + 32), c2, 0, 0, 0);
        c2 = __builtin_amdgcn_mfma_f32_16x16x32_bf16(as_bf(b23), ld_frag(Bb + 48), c2, 0, 0, 0);
        int hw = hw0 + 16 + m16;
        if (hw < HW_) {
            #pragma unroll
            for (int r = 0; r < 4; ++r) {
                int o2 = m2b * 16 + quad * 4 + r;
                if (o2 >= OUTD_) continue;
                float aa = c2[r] + B2[o2];
                unsigned dst; float val;
                if (o2 < 36) {
                    int an9 = o2 >> 2, kk = o2 & 3;
                    val = (kk < 2) ? (sigmoidf_(aa) - 0.5f) : aa;
                    dst = OFFS_OFF + b * 1764 + an9 * 196 + kk * 49 + hw;
                } else if (o2 < 45) {
                    val = sigmoidf_(aa);
                    dst = CONF_OFF + b * 441 + (o2 - 36) * 49 + hw;
                } else {
                    val = aa;
                    dst = CLS_OFF + b * 980 + (o2 - 45) * 49 + hw;
                }
                out[dst] = val;
            }
        }
    }

    // ---- IoU: wave-per-p (uniform P), g = lane (<40), coalesced 160B stores ----
    {
        int gl = (lane < NGT_) ? lane : 0;
        const float* gb = bbox + b * 200 + gl * 5;
        float gx1 = gb[0], gy1 = gb[1], gx2 = gb[2], gy2 = gb[3];
        float gA = (gx2 - gx1) * (gy2 - gy1);
        const int pstart = half ? 221 : 0;
        const int pend   = half ? NP_ : 221;
        for (int p = pstart + w; p < pend; p += 8) {
            int a9 = p / 49, r = p - a9 * 49;
            float cx = grd[b * 98 + 2 * r], cy = grd[b * 98 + 2 * r + 1];
            float hx = anc[2 * a9] * 0.5f,  hy = anc[2 * a9 + 1] * 0.5f;
            float px1 = cx - hx, py1 = cy - hy, px2 = cx + hx, py2 = cy + hy;
            float pA = (px2 - px1) * (py2 - py1);
            float legal = (fminf(fminf(px1, py1), fminf(px2, py2)) > 0.f) ? 1.f : 0.f;
            float tlx = fmaxf(px1, gx1), tly = fmaxf(py1, gy1);
            float brx = fminf(px2, gx2), bry = fminf(py2, gy2);
            float dx = fmaxf(brx - tlx, 0.f), dy = fmaxf(bry - tly, 0.f);
            float inter = dx * dy * legal;
            float iou = inter / (gA + pA - inter);
            if (lane < NGT_)
                out[IOU_OFF + b * (NP_ * NGT_) + p * 40 + lane] = iou;
        }
    }
}

extern "C" void kernel_launch(void* const* d_in, const int* in_sizes, int n_in,
                              void* d_out, int out_size, void* d_ws, size_t ws_size,
                              hipStream_t stream) {
    const float* F  = (const float*)d_in[0];
    const float* G  = (const float*)d_in[1];
    const float* BB = (const float*)d_in[2];
    const float* AN = (const float*)d_in[3];
    const float* W1 = (const float*)d_in[4];
    const float* B1 = (const float*)d_in[5];
    const float* W2 = (const float*)d_in[6];
    const float* B2 = (const float*)d_in[7];
    float* out = (float*)d_out;
    unsigned* wsu = (unsigned*)d_ws;

    // harness provides ~268 MB ws; we need 348 KB
    prep_w<<<340, 256, 0, stream>>>(W1, W2, wsu);
    fused_main<<<512, 512, 0, stream>>>(F, G, BB, AN, wsu, B1, B2, out);
}

// Round 9
// 133.403 us; speedup vs baseline: 1.1029x; 1.1029x over previous
//
#include <hip/hip_runtime.h>

// SingleStageDetector, R9 = R8 + deep-pipelined staging (16 loads in flight),
// 2-deep A prefetch, unrolled IoU. Structure (proven correct in R8):
// prep_w (W1/W2 -> frag images in ws) + fused_main (grid 512 = image x
// hw-half, 512 thr = 8 waves, 80 KB LDS => 2 blocks/CU):
//   stage F 32-hw slice -> LDS (bf16-pair, XOR-swizzled)
//   -> barrier-free 40-step MFMA K-loop (A global frags, B ds_read_b128)
//   -> h (bias+leaky) -> aliased LDS -> GEMM2 MFMA + epilogue -> register IoU.

#define CIN_  1280
#define HW_   49
#define HID_  128
#define OUTD_ 65
#define NGT_  40
#define NP_   441

// flat output offsets (elements), reference return order
#define CONF_OFF 0
#define OFFS_OFF 112896   // 256*9*49
#define CLS_OFF  564480   // + 256*9*4*49
#define IOU_OFF  815360   // + 256*20*49 ; total 5,331,200

// ws layout (u32): W1f frags ((K32*8+mt)*64+lane)*4+sub, then W2f frags
#define WS_W1F_U32 81920u
#define WS_W2F_U32 5120u

typedef __bf16 bf16x8 __attribute__((ext_vector_type(8)));
typedef float  f32x4  __attribute__((ext_vector_type(4)));

__device__ __forceinline__ unsigned pack2bf(float lo, float hi) {
    unsigned a = __float_as_uint(lo);
    unsigned b = __float_as_uint(hi);
    a = (a + 0x7FFFu + ((a >> 16) & 1u)) >> 16;   // RNE f32->bf16
    b = (b + 0x7FFFu + ((b >> 16) & 1u)) >> 16;
    return a | (b << 16);
}
__device__ __forceinline__ float sigmoidf_(float v) { return 1.f / (1.f + __expf(-v)); }

__device__ __forceinline__ bf16x8 ld_frag(const unsigned* p) {
    union { uint4 u; bf16x8 v; } x;
    x.u = *(const uint4*)p;                       // 16B-aligned ds_read_b128
    return x.v;
}
__device__ __forceinline__ bf16x8 as_bf(uint4 u) {
    union { uint4 u; bf16x8 v; } x; x.u = u; return x.v;
}

// ---------------------------------------------------------------------------
// prep_w: W1 (128,1280) + W2 (65,128) -> fragment-ready bf16 images. (R8.)
// ---------------------------------------------------------------------------
__global__ __launch_bounds__(256) void prep_w(
    const float* __restrict__ W1, const float* __restrict__ W2,
    unsigned* __restrict__ ws)
{
    int X = blockIdx.x * 256 + threadIdx.x;       // 0..87039
    if (X < (int)WS_W1F_U32) {
        int sub = X & 3, lane = (X >> 2) & 63, f = X >> 8;
        int mt = f & 7, K32 = f >> 3;
        int o = mt * 16 + (lane & 15);
        int c = K32 * 32 + (lane >> 4) * 8 + sub * 2;
        float2 v = *(const float2*)(W1 + o * CIN_ + c);
        ws[X] = pack2bf(v.x, v.y);
    } else {
        int Y = X - (int)WS_W1F_U32;              // 0..5119
        int sub = Y & 3, lane = (Y >> 2) & 63, f = Y >> 8;
        int mt2 = f % 5, ks2 = f / 5;
        int o2 = mt2 * 16 + (lane & 15);
        int c = ks2 * 32 + (lane >> 4) * 8 + sub * 2;
        unsigned val = 0;
        if (o2 < OUTD_) {
            float2 v = *(const float2*)(W2 + o2 * HID_ + c);
            val = pack2bf(v.x, v.y);
        }
        ws[WS_W1F_U32 + Y] = val;
    }
}

// ---------------------------------------------------------------------------
// fused_main: block = (b, half). LDS: smF 32 rows x 640 u32, XOR swizzle on
// 16B blocks (phys_cb = cb ^ (row&7)). smHT (32x68 u32) aliases smF.
// ---------------------------------------------------------------------------
__global__ __launch_bounds__(512, 4) void fused_main(
    const float* __restrict__ F,     // (256,1280,7,7)
    const float* __restrict__ grd,   // (256,7,7,2)
    const float* __restrict__ bbox,  // (256,40,5)
    const float* __restrict__ anc,   // (9,2)
    const unsigned* __restrict__ wsW,
    const float* __restrict__ B1,    // (128,)
    const float* __restrict__ B2,    // (65,)
    float* __restrict__ out)
{
    __shared__ __align__(16) unsigned lds[32 * 640];   // 81,920 B
    unsigned* smHT = lds;                              // aliased after K-loop

    const int tid  = threadIdx.x;
    const int b    = blockIdx.x >> 1;
    const int half = blockIdx.x & 1;
    const int lane = tid & 63;
    const int w    = tid >> 6;         // 0..7 = GEMM1 m-tile
    const int quad = lane >> 4;
    const int m16  = lane & 15;
    const int hw0  = half * 32;

    const float* Fb = F + b * (CIN_ * HW_);

    // ---- stage F hw-slice, deep-pipelined: 5 groups x (16 loads -> 8 writes) ----
    // i = it*512+tid -> cp = i>>5 (0..639), row = i&31, hw = hw0+row.
    // Pad rows (hw>=49) -> zeros.
    #pragma unroll
    for (int g = 0; g < 5; ++g) {
        float f0[8], f1[8];
        #pragma unroll
        for (int u = 0; u < 8; ++u) {
            int i   = (g * 8 + u) * 512 + tid;
            int cp  = i >> 5;
            int row = i & 31;
            int hw  = hw0 + row;
            bool ok = hw < HW_;
            f0[u] = ok ? Fb[(2 * cp) * HW_ + hw] : 0.f;
            f1[u] = ok ? Fb[(2 * cp + 1) * HW_ + hw] : 0.f;
        }
        #pragma unroll
        for (int u = 0; u < 8; ++u) {
            int i   = (g * 8 + u) * 512 + tid;
            int cp  = i >> 5;
            int row = i & 31;
            int cb = cp >> 2, sub = cp & 3;
            lds[row * 640 + ((cb ^ (row & 7)) << 2) + sub] = pack2bf(f0[u], f1[u]);
        }
    }
    __syncthreads();

    // ---- GEMM1 K-loop: 40 steps, barrier-free, 2-deep A prefetch ----
    const uint4* Ap = (const uint4*)wsW + w * 64 + lane;   // + K32*8*64
    const unsigned* r0b = lds + m16 * 640;
    const unsigned* r1b = lds + (16 + m16) * 640;
    const int swz = (m16 & 7);

    f32x4 acc0 = (f32x4)(0.f), acc1 = (f32x4)(0.f);
    uint4 a0 = Ap[0];
    uint4 a1 = Ap[512];
    for (int k = 0; k < 40; ++k) {
        uint4 an;
        if (k < 38) an = Ap[(k + 2) * 512];                // prefetch k+2
        int off = ((k * 4 + quad) ^ swz) << 2;
        bf16x8 A = as_bf(a0);
        bf16x8 b0 = ld_frag(r0b + off);
        bf16x8 b1 = ld_frag(r1b + off);
        acc0 = __builtin_amdgcn_mfma_f32_16x16x32_bf16(A, b0, acc0, 0, 0, 0);
        acc1 = __builtin_amdgcn_mfma_f32_16x16x32_bf16(A, b1, acc1, 0, 0, 0);
        a0 = a1; a1 = an;
    }

    // prefetch GEMM2 A-frags (global, independent of LDS)
    const int m2a = w % 5, nt2a = w / 5;                   // tile w of 10
    const uint4* A2p = (const uint4*)(wsW + WS_W1F_U32) + m2a * 64 + lane;
    uint4 a20 = A2p[0], a21 = A2p[320], a22 = A2p[640], a23 = A2p[960];

    __syncthreads();   // all smF reads done; safe to alias smHT

    // ---- h: bias + leaky, packed o-pairs -> smHT[hwlocal*68 + o/2] ----
    #pragma unroll
    for (int nt = 0; nt < 2; ++nt) {
        f32x4 ac = nt ? acc1 : acc0;
        int r0 = nt * 16 + m16;
        #pragma unroll
        for (int rp = 0; rp < 2; ++rp) {
            int o0 = w * 16 + quad * 4 + 2 * rp;
            float v0 = ac[2 * rp]     + B1[o0];
            float v1 = ac[2 * rp + 1] + B1[o0 + 1];
            v0 = v0 > 0.f ? v0 : 0.01f * v0;
            v1 = v1 > 0.f ? v1 : 0.01f * v1;
            smHT[r0 * 68 + (o0 >> 1)] = pack2bf(v0, v1);
        }
    }
    __syncthreads();   // smHT ready

    // ---- GEMM2: tile (m2, nt2); wave w -> tile w; waves 0,1 also tiles 8,9 ----
    {
        f32x4 c2 = (f32x4)(0.f);
        const unsigned* Bb = smHT + (nt2a * 16 + m16) * 68 + quad * 4;
        c2 = __builtin_amdgcn_mfma_f32_16x16x32_bf16(as_bf(a20), ld_frag(Bb +  0), c2, 0, 0, 0);
        c2 = __builtin_amdgcn_mfma_f32_16x16x32_bf16(as_bf(a21), ld_frag(Bb + 16), c2, 0, 0, 0);
        c2 = __builtin_amdgcn_mfma_f32_16x16x32_bf16(as_bf(a22), ld_frag(Bb + 32), c2, 0, 0, 0);
        c2 = __builtin_amdgcn_mfma_f32_16x16x32_bf16(as_bf(a23), ld_frag(Bb + 48), c2, 0, 0, 0);
        int hw = hw0 + nt2a * 16 + m16;
        if (hw < HW_) {
            #pragma unroll
            for (int r = 0; r < 4; ++r) {
                int o2 = m2a * 16 + quad * 4 + r;
                if (o2 >= OUTD_) continue;
                float aa = c2[r] + B2[o2];
                unsigned dst; float val;
                if (o2 < 36) {
                    int an9 = o2 >> 2, kk = o2 & 3;
                    val = (kk < 2) ? (sigmoidf_(aa) - 0.5f) : aa;
                    dst = OFFS_OFF + b * 1764 + an9 * 196 + kk * 49 + hw;
                } else if (o2 < 45) {
                    val = sigmoidf_(aa);
                    dst = CONF_OFF + b * 441 + (o2 - 36) * 49 + hw;
                } else {
                    val = aa;
                    dst = CLS_OFF + b * 980 + (o2 - 45) * 49 + hw;
                }
                out[dst] = val;
            }
        }
    }
    if (w < 2) {       // tiles 8,9: m2 = 3+w, nt2 = 1
        const int m2b = 3 + w;
        const uint4* A3p = (const uint4*)(wsW + WS_W1F_U32) + m2b * 64 + lane;
        uint4 b20 = A3p[0], b21 = A3p[320], b22 = A3p[640], b23 = A3p[960];
        f32x4 c2 = (f32x4)(0.f);
        const unsigned* Bb = smHT + (16 + m16) * 68 + quad * 4;
        c2 = __builtin_amdgcn_mfma_f32_16x16x32_bf16(as_bf(b20), ld_frag(Bb +  0), c2, 0, 0, 0);
        c2 = __builtin_amdgcn_mfma_f32_16x16x32_bf16(as_bf(b21), ld_frag(Bb + 16), c2, 0, 0, 0);
        c2 = __builtin_amdgcn_mfma_f32_16x16x32_bf16(as_bf(b22), ld_frag(Bb + 32), c2, 0, 0, 0);
        c2 = __builtin_amdgcn_mfma_f32_16x16x32_bf16(as_bf(b23), ld_frag(Bb + 48), c2, 0, 0, 0);
        int hw = hw0 + 16 + m16;
        if (hw < HW_) {
            #pragma unroll
            for (int r = 0; r < 4; ++r) {
                int o2 = m2b * 16 + quad * 4 + r;
                if (o2 >= OUTD_) continue;
                float aa = c2[r] + B2[o2];
                unsigned dst; float val;
                if (o2 < 36) {
                    int an9 = o2 >> 2, kk = o2 & 3;
                    val = (kk < 2) ? (sigmoidf_(aa) - 0.5f) : aa;
                    dst = OFFS_OFF + b * 1764 + an9 * 196 + kk * 49 + hw;
                } else if (o2 < 45) {
                    val = sigmoidf_(aa);
                    dst = CONF_OFF + b * 441 + (o2 - 36) * 49 + hw;
                } else {
                    val = aa;
                    dst = CLS_OFF + b * 980 + (o2 - 45) * 49 + hw;
                }
                out[dst] = val;
            }
        }
    }

    // ---- IoU: wave-uniform p, g = lane (<40), unrolled, coalesced stores ----
    {
        int gl = (lane < NGT_) ? lane : 0;
        const float* gb = bbox + b * 200 + gl * 5;
        float gx1 = gb[0], gy1 = gb[1], gx2 = gb[2], gy2 = gb[3];
        float gA = (gx2 - gx1) * (gy2 - gy1);
        const int pstart = half ? 221 : 0;
        const int pend   = half ? NP_ : 221;
        #pragma unroll 4
        for (int p = pstart + w; p < pend; p += 8) {
            int a9 = p / 49, r = p - a9 * 49;
            float2 ct = *(const float2*)(grd + b * 98 + 2 * r);
            float hx = anc[2 * a9] * 0.5f,  hy = anc[2 * a9 + 1] * 0.5f;
            float px1 = ct.x - hx, py1 = ct.y - hy, px2 = ct.x + hx, py2 = ct.y + hy;
            float pA = (px2 - px1) * (py2 - py1);
            float legal = (fminf(fminf(px1, py1), fminf(px2, py2)) > 0.f) ? 1.f : 0.f;
            float tlx = fmaxf(px1, gx1), tly = fmaxf(py1, gy1);
            float brx = fminf(px2, gx2), bry = fminf(py2, gy2);
            float dx = fmaxf(brx - tlx, 0.f), dy = fmaxf(bry - tly, 0.f);
            float inter = dx * dy * legal;
            float iou = inter / (gA + pA - inter);
            if (lane < NGT_)
                out[IOU_OFF + b * (NP_ * NGT_) + p * 40 + lane] = iou;
        }
    }
}

extern "C" void kernel_launch(void* const* d_in, const int* in_sizes, int n_in,
                              void* d_out, int out_size, void* d_ws, size_t ws_size,
                              hipStream_t stream) {
    const float* F  = (const float*)d_in[0];
    const float* G  = (const float*)d_in[1];
    const float* BB = (const float*)d_in[2];
    const float* AN = (const float*)d_in[3];
    const float* W1 = (const float*)d_in[4];
    const float* B1 = (const float*)d_in[5];
    const float* W2 = (const float*)d_in[6];
    const float* B2 = (const float*)d_in[7];
    float* out = (float*)d_out;
    unsigned* wsu = (unsigned*)d_ws;

    prep_w<<<340, 256, 0, stream>>>(W1, W2, wsu);
    fused_main<<<512, 512, 0, stream>>>(F, G, BB, AN, wsu, B1, B2, out);
}